// Round 1
// baseline (82.764 us; speedup 1.0000x reference)
//
#include <hip/hip_runtime.h>

// Chamfer distance, B=4, N=M=8192, fp32 points in R^3.
// out = mean_i min_j ||x_i - y_j||^2 + mean_j min_i ||x_i - y_j||^2
//
// Structure: symmetric "row-min" kernel launched twice (x->y, y->x).
// Each block: (batch, x-tile of 1024 pts, y-segment of 256 pts).
// y-segment staged in LDS (3 KB); inner reads are wave-uniform (broadcast).
// Each thread holds ITEMS=4 x-points in registers -> 28 VALU ops per
// 3 LDS broadcast reads (VALU-bound). Cross-segment min via atomicMin on
// float bits (valid since d >= 0); deterministic (min is order-independent).

#define BATCH 4
#define NPTS 8192
#define TPB 256
#define ITEMS 4
#define XTILE (TPB * ITEMS)        // 1024
#define TILES (NPTS / XTILE)       // 8
#define SEGS 32
#define SEGLEN (NPTS / SEGS)       // 256
#define LOG_SEGS 5
#define LOG_TILES 3

__global__ void init_kernel(unsigned int* w, int n) {
    int idx = blockIdx.x * blockDim.x + threadIdx.x;
    if (idx < n) w[idx] = 0x7F800000u;  // +inf bits
}

__global__ __launch_bounds__(TPB) void chamfer_min_kernel(
    const float* __restrict__ pa,          // [BATCH, NPTS, 3] query points
    const float* __restrict__ pb,          // [BATCH, NPTS, 3] reference points
    unsigned int* __restrict__ best_bits)  // [BATCH, NPTS] float bits
{
    const int blk  = blockIdx.x;
    const int seg  = blk & (SEGS - 1);
    const int tile = (blk >> LOG_SEGS) & (TILES - 1);
    const int b    = blk >> (LOG_SEGS + LOG_TILES);
    const int t    = threadIdx.x;

    __shared__ float sy[SEGLEN * 3];

    // stage this block's y-segment into LDS (768 floats, 3 per thread, coalesced)
    {
        const float* src = pb + ((size_t)b * NPTS + (size_t)seg * SEGLEN) * 3;
        sy[t]           = src[t];
        sy[t + TPB]     = src[t + TPB];
        sy[t + 2 * TPB] = src[t + 2 * TPB];
    }

    // this thread's x points (4 of them, strided by TPB within the tile)
    float ax[ITEMS], ay[ITEMS], az[ITEMS], best[ITEMS];
    const int ibase = tile * XTILE + t;
#pragma unroll
    for (int it = 0; it < ITEMS; ++it) {
        const float* p = pa + ((size_t)b * NPTS + ibase + it * TPB) * 3;
        ax[it] = p[0]; ay[it] = p[1]; az[it] = p[2];
        best[it] = __builtin_inff();
    }

    __syncthreads();

#pragma unroll 4
    for (int j = 0; j < SEGLEN; ++j) {
        const float yx = sy[3 * j + 0];   // wave-uniform -> LDS broadcast
        const float yy = sy[3 * j + 1];
        const float yz = sy[3 * j + 2];
#pragma unroll
        for (int it = 0; it < ITEMS; ++it) {
            const float dx = ax[it] - yx;
            const float dy = ay[it] - yy;
            const float dz = az[it] - yz;
            float d = dx * dx;
            d = fmaf(dy, dy, d);
            d = fmaf(dz, dz, d);
            best[it] = fminf(best[it], d);
        }
    }

#pragma unroll
    for (int it = 0; it < ITEMS; ++it) {
        atomicMin(&best_bits[(size_t)b * NPTS + ibase + it * TPB],
                  __float_as_uint(best[it]));
    }
}

__global__ void reduce_kernel(const unsigned int* __restrict__ u1,
                              const unsigned int* __restrict__ u2,
                              float* __restrict__ out)
{
    const int n = BATCH * NPTS;
    double s1 = 0.0, s2 = 0.0;
    for (int i = threadIdx.x; i < n; i += blockDim.x) {
        s1 += (double)__uint_as_float(u1[i]);
        s2 += (double)__uint_as_float(u2[i]);
    }
    for (int off = 32; off > 0; off >>= 1) {
        s1 += __shfl_down(s1, off, 64);
        s2 += __shfl_down(s2, off, 64);
    }
    __shared__ double l1[16], l2[16];
    const int wave = threadIdx.x >> 6;
    if ((threadIdx.x & 63) == 0) { l1[wave] = s1; l2[wave] = s2; }
    __syncthreads();
    if (threadIdx.x == 0) {
        double t1 = 0.0, t2 = 0.0;
        const int nw = blockDim.x >> 6;
        for (int w = 0; w < nw; ++w) { t1 += l1[w]; t2 += l2[w]; }
        out[0] = (float)(t1 / n + t2 / n);
    }
}

extern "C" void kernel_launch(void* const* d_in, const int* in_sizes, int n_in,
                              void* d_out, int out_size, void* d_ws, size_t ws_size,
                              hipStream_t stream) {
    const float* xyz1 = (const float*)d_in[0];
    const float* xyz2 = (const float*)d_in[1];
    float* out = (float*)d_out;
    unsigned int* u1 = (unsigned int*)d_ws;           // [BATCH*NPTS] min bits (dir 1)
    unsigned int* u2 = u1 + BATCH * NPTS;             // [BATCH*NPTS] min bits (dir 2)

    const int total = 2 * BATCH * NPTS;               // 64 Ki entries, 256 KB
    init_kernel<<<(total + 255) / 256, 256, 0, stream>>>(u1, total);

    const int grid = BATCH * TILES * SEGS;            // 1024 blocks
    chamfer_min_kernel<<<grid, TPB, 0, stream>>>(xyz1, xyz2, u1);
    chamfer_min_kernel<<<grid, TPB, 0, stream>>>(xyz2, xyz1, u2);

    reduce_kernel<<<1, 1024, 0, stream>>>(u1, u2, out);
}

// Round 2
// 58.649 us; speedup vs baseline: 1.4112x; 1.4112x over previous
//
#include <hip/hip_runtime.h>

// Chamfer distance, B=4, N=M=8192, fp32 points in R^3.
// out = mean_i min_j ||x_i - y_j||^2 + mean_j min_i ||x_i - y_j||^2
//
// VALU-issue-bound (inputs are 768 KB, fully L2-resident). Per pair:
//   d' = c_j - x.y  (3 chained FMAs; c_j = 0.5*|y_j|^2 staged in LDS float4)
//   min via v_min3 (pairs of j)  -> ~3.5 VALU ops/pair
// Actual distance recovered at epilogue: d = 2*best' + |x|^2.
// Cross-segment combine: atomicMin on monotone-mapped float keys
// (d' may be negative -> sign-flip uint mapping). Deterministic.

#define BATCH 4
#define NPTS 8192
#define TPB 256
#define ITEMS 4
#define XTILE (TPB * ITEMS)        // 1024
#define TILES (NPTS / XTILE)       // 8
#define SEGS 16
#define SEGLEN (NPTS / SEGS)       // 512

__global__ __launch_bounds__(TPB) void chamfer_min_kernel(
    const float* __restrict__ xyz1,
    const float* __restrict__ xyz2,
    unsigned int* __restrict__ bits1,   // [BATCH*NPTS] keys, dir x->y
    unsigned int* __restrict__ bits2)   // [BATCH*NPTS] keys, dir y->x
{
    const int blk  = blockIdx.x;
    const int seg  = blk & (SEGS - 1);
    const int tile = (blk >> 4) & (TILES - 1);
    const int b    = (blk >> 7) & (BATCH - 1);
    const int dir  = blk >> 9;
    const int t    = threadIdx.x;

    const float* pa = dir ? xyz2 : xyz1;          // query points
    const float* pb = dir ? xyz1 : xyz2;          // reference points
    unsigned int* best_bits = dir ? bits2 : bits1;

    __shared__ float4 sy[SEGLEN];                  // (yx, yy, yz, 0.5*|y|^2)

    {
        const float* src = pb + ((size_t)b * NPTS + (size_t)seg * SEGLEN) * 3;
#pragma unroll
        for (int p = t; p < SEGLEN; p += TPB) {
            const float yx = src[3 * p + 0];
            const float yy = src[3 * p + 1];
            const float yz = src[3 * p + 2];
            const float c  = 0.5f * (yx * yx + yy * yy + yz * yz);
            sy[p] = make_float4(yx, yy, yz, c);
        }
    }

    // this thread's x points (4, strided by TPB within the 1024-pt tile)
    float ax[ITEMS], ay[ITEMS], az[ITEMS], sx[ITEMS], best[ITEMS];
    const int ibase = tile * XTILE + t;
#pragma unroll
    for (int it = 0; it < ITEMS; ++it) {
        const float* p = pa + ((size_t)b * NPTS + ibase + it * TPB) * 3;
        ax[it] = p[0]; ay[it] = p[1]; az[it] = p[2];
        sx[it] = ax[it] * ax[it] + ay[it] * ay[it] + az[it] * az[it];
        best[it] = __builtin_inff();
    }

    __syncthreads();

#pragma unroll 2
    for (int j = 0; j < SEGLEN; j += 2) {
        const float4 q0 = sy[j];       // uniform address -> LDS broadcast
        const float4 q1 = sy[j + 1];
#pragma unroll
        for (int it = 0; it < ITEMS; ++it) {
            // d' = c - x.y : 3 chained FMAs (neg modifier is free)
            const float d0 = fmaf(-ax[it], q0.x,
                             fmaf(-ay[it], q0.y,
                             fmaf(-az[it], q0.z, q0.w)));
            const float d1 = fmaf(-ax[it], q1.x,
                             fmaf(-ay[it], q1.y,
                             fmaf(-az[it], q1.z, q1.w)));
            best[it] = fminf(best[it], fminf(d0, d1));   // -> v_min3_f32
        }
    }

#pragma unroll
    for (int it = 0; it < ITEMS; ++it) {
        const float d = fmaf(2.0f, best[it], sx[it]);    // |x-y|^2 (may be ~ -1e-7)
        const unsigned int u = __float_as_uint(d);
        const unsigned int key = u ^ ((u >> 31) ? 0xFFFFFFFFu : 0x80000000u);
        atomicMin(&best_bits[(size_t)b * NPTS + ibase + it * TPB], key);
    }
}

__device__ inline float key_decode(unsigned int key) {
    const unsigned int u = (key & 0x80000000u) ? (key ^ 0x80000000u) : ~key;
    return __uint_as_float(u);
}

__global__ __launch_bounds__(1024) void reduce_kernel(
    const unsigned int* __restrict__ u1,
    const unsigned int* __restrict__ u2,
    float* __restrict__ out)
{
    const int n4 = BATCH * NPTS / 4;               // 8192 uint4 per array
    const uint4* v1 = (const uint4*)u1;
    const uint4* v2 = (const uint4*)u2;
    double s1 = 0.0, s2 = 0.0;
    for (int i = threadIdx.x; i < n4; i += blockDim.x) {
        const uint4 a = v1[i];
        const uint4 c = v2[i];
        s1 += (double)key_decode(a.x) + (double)key_decode(a.y)
            + (double)key_decode(a.z) + (double)key_decode(a.w);
        s2 += (double)key_decode(c.x) + (double)key_decode(c.y)
            + (double)key_decode(c.z) + (double)key_decode(c.w);
    }
    for (int off = 32; off > 0; off >>= 1) {
        s1 += __shfl_down(s1, off, 64);
        s2 += __shfl_down(s2, off, 64);
    }
    __shared__ double l1[16], l2[16];
    const int wave = threadIdx.x >> 6;
    if ((threadIdx.x & 63) == 0) { l1[wave] = s1; l2[wave] = s2; }
    __syncthreads();
    if (threadIdx.x == 0) {
        double t1 = 0.0, t2 = 0.0;
        const int nw = blockDim.x >> 6;
        for (int w = 0; w < nw; ++w) { t1 += l1[w]; t2 += l2[w]; }
        const double n = (double)(BATCH * NPTS);
        out[0] = (float)(t1 / n + t2 / n);
    }
}

extern "C" void kernel_launch(void* const* d_in, const int* in_sizes, int n_in,
                              void* d_out, int out_size, void* d_ws, size_t ws_size,
                              hipStream_t stream) {
    const float* xyz1 = (const float*)d_in[0];
    const float* xyz2 = (const float*)d_in[1];
    float* out = (float*)d_out;
    unsigned int* u1 = (unsigned int*)d_ws;
    unsigned int* u2 = u1 + BATCH * NPTS;

    // init keys to 0xFFFFFFFF (max key)
    hipMemsetAsync(u1, 0xFF, 2 * BATCH * NPTS * sizeof(unsigned int), stream);

    const int grid = 2 * BATCH * TILES * SEGS;     // 1024 blocks, both directions
    chamfer_min_kernel<<<grid, TPB, 0, stream>>>(xyz1, xyz2, u1, u2);

    reduce_kernel<<<1, 1024, 0, stream>>>(u1, u2, out);
}

// Round 3
// 57.121 us; speedup vs baseline: 1.4489x; 1.0267x over previous
//
#include <hip/hip_runtime.h>

// Chamfer distance, B=4, N=M=8192, fp32 points in R^3.
// out = mean_i min_j ||x_i - y_j||^2 + mean_j min_i ||x_i - y_j||^2
//
// VALU-issue-bound (inputs 768 KB, L2-resident). Per pair:
//   d' = c_j - x.y  (3 chained FMAs; c_j = 0.5*|y_j|^2 staged in LDS float4)
//   min via v_min3 over j-pairs -> ~3.5 VALU ops/pair.
// ITEMS=8 x-points per thread so the 1 ds_read_b128 per j amortizes over
// 28 VALU ops (R1 showed ITEMS=4 oversubscribed the per-CU LDS pipe ~1.7x).
// Cross-segment combine: atomicMin on monotone-mapped float keys.

#define BATCH 4
#define NPTS 8192
#define TPB 256
#define ITEMS 8
#define XTILE (TPB * ITEMS)        // 2048
#define TILES (NPTS / XTILE)       // 4
#define SEGS 32
#define SEGLEN (NPTS / SEGS)       // 256

__global__ __launch_bounds__(TPB) void chamfer_min_kernel(
    const float* __restrict__ xyz1,
    const float* __restrict__ xyz2,
    unsigned int* __restrict__ bits1,   // [BATCH*NPTS] keys, dir x->y
    unsigned int* __restrict__ bits2)   // [BATCH*NPTS] keys, dir y->x
{
    const int blk  = blockIdx.x;
    const int seg  = blk & (SEGS - 1);
    const int tile = (blk >> 5) & (TILES - 1);
    const int b    = (blk >> 7) & (BATCH - 1);
    const int dir  = blk >> 9;
    const int t    = threadIdx.x;

    const float* pa = dir ? xyz2 : xyz1;          // query points
    const float* pb = dir ? xyz1 : xyz2;          // reference points
    unsigned int* best_bits = dir ? bits2 : bits1;

    __shared__ float4 sy[SEGLEN];                  // (yx, yy, yz, 0.5*|y|^2)

    if (t < SEGLEN) {
        const float* src = pb + ((size_t)b * NPTS + (size_t)seg * SEGLEN + t) * 3;
        const float yx = src[0];
        const float yy = src[1];
        const float yz = src[2];
        const float c  = 0.5f * (yx * yx + yy * yy + yz * yz);
        sy[t] = make_float4(yx, yy, yz, c);
    }

    // this thread's x points (8, strided by TPB within the 2048-pt tile)
    float ax[ITEMS], ay[ITEMS], az[ITEMS], sx[ITEMS], best[ITEMS];
    const int ibase = tile * XTILE + t;
#pragma unroll
    for (int it = 0; it < ITEMS; ++it) {
        const float* p = pa + ((size_t)b * NPTS + ibase + it * TPB) * 3;
        ax[it] = p[0]; ay[it] = p[1]; az[it] = p[2];
        sx[it] = ax[it] * ax[it] + ay[it] * ay[it] + az[it] * az[it];
        best[it] = __builtin_inff();
    }

    __syncthreads();

#pragma unroll 2
    for (int j = 0; j < SEGLEN; j += 2) {
        const float4 q0 = sy[j];       // uniform address -> LDS broadcast
        const float4 q1 = sy[j + 1];
#pragma unroll
        for (int it = 0; it < ITEMS; ++it) {
            // d' = c - x.y : 3 chained FMAs (neg modifier is free)
            const float d0 = fmaf(-ax[it], q0.x,
                             fmaf(-ay[it], q0.y,
                             fmaf(-az[it], q0.z, q0.w)));
            const float d1 = fmaf(-ax[it], q1.x,
                             fmaf(-ay[it], q1.y,
                             fmaf(-az[it], q1.z, q1.w)));
            best[it] = fminf(best[it], fminf(d0, d1));   // -> v_min3_f32
        }
    }

#pragma unroll
    for (int it = 0; it < ITEMS; ++it) {
        const float d = fmaf(2.0f, best[it], sx[it]);    // |x-y|^2
        const unsigned int u = __float_as_uint(d);
        const unsigned int key = u ^ ((u >> 31) ? 0xFFFFFFFFu : 0x80000000u);
        atomicMin(&best_bits[(size_t)b * NPTS + ibase + it * TPB], key);
    }
}

__device__ inline float key_decode(unsigned int key) {
    const unsigned int u = (key & 0x80000000u) ? (key ^ 0x80000000u) : ~key;
    return __uint_as_float(u);
}

__global__ __launch_bounds__(1024) void reduce_kernel(
    const unsigned int* __restrict__ u1,
    const unsigned int* __restrict__ u2,
    float* __restrict__ out)
{
    const int n4 = BATCH * NPTS / 4;               // 8192 uint4 per array
    const uint4* v1 = (const uint4*)u1;
    const uint4* v2 = (const uint4*)u2;
    double s1 = 0.0, s2 = 0.0;
    for (int i = threadIdx.x; i < n4; i += blockDim.x) {
        const uint4 a = v1[i];
        const uint4 c = v2[i];
        s1 += (double)key_decode(a.x) + (double)key_decode(a.y)
            + (double)key_decode(a.z) + (double)key_decode(a.w);
        s2 += (double)key_decode(c.x) + (double)key_decode(c.y)
            + (double)key_decode(c.z) + (double)key_decode(c.w);
    }
    for (int off = 32; off > 0; off >>= 1) {
        s1 += __shfl_down(s1, off, 64);
        s2 += __shfl_down(s2, off, 64);
    }
    __shared__ double l1[16], l2[16];
    const int wave = threadIdx.x >> 6;
    if ((threadIdx.x & 63) == 0) { l1[wave] = s1; l2[wave] = s2; }
    __syncthreads();
    if (threadIdx.x == 0) {
        double t1 = 0.0, t2 = 0.0;
        const int nw = blockDim.x >> 6;
        for (int w = 0; w < nw; ++w) { t1 += l1[w]; t2 += l2[w]; }
        const double n = (double)(BATCH * NPTS);
        out[0] = (float)(t1 / n + t2 / n);
    }
}

extern "C" void kernel_launch(void* const* d_in, const int* in_sizes, int n_in,
                              void* d_out, int out_size, void* d_ws, size_t ws_size,
                              hipStream_t stream) {
    const float* xyz1 = (const float*)d_in[0];
    const float* xyz2 = (const float*)d_in[1];
    float* out = (float*)d_out;
    unsigned int* u1 = (unsigned int*)d_ws;
    unsigned int* u2 = u1 + BATCH * NPTS;

    // init keys to 0xFFFFFFFF (max key)
    hipMemsetAsync(u1, 0xFF, 2 * BATCH * NPTS * sizeof(unsigned int), stream);

    const int grid = 2 * BATCH * TILES * SEGS;     // 1024 blocks, both directions
    chamfer_min_kernel<<<grid, TPB, 0, stream>>>(xyz1, xyz2, u1, u2);

    reduce_kernel<<<1, 1024, 0, stream>>>(u1, u2, out);
}